// Round 5
// baseline (302.973 us; speedup 1.0000x reference)
//
#include <hip/hip_runtime.h>
#include <math.h>

// Problem constants (fixed by reference: B=8, C=3, H=W=1024)
constexpr int BC = 24;     // B*C point-set pairs
constexpr int N  = 1024;   // points per set
constexpr int D  = 1024;   // point dimension
constexpr int TILE = 128;  // 128x128 output tile per block
constexpr int SKF = 40;    // fallback kernel LDS stride (bf16)

typedef short short8 __attribute__((ext_vector_type(8)));
typedef float f32x4  __attribute__((ext_vector_type(4)));

#define FINF 3.402823466e+38f

// Swizzled (MFMA-fragment-ready) layout, per (tensor, bc):
//   element (row, k) -> tile (R = row>>4, K = k>>5), lane = (row&15) | (((k>>3)&3)<<4),
//   j = k&7; flat short index = ((R*32 + K)*64 + lane)*8 + j.
// A wave's 16x16x32 fragment load = tile base + lane*8 shorts = one coalesced 1-KB
// global_load_dwordx4. Same formula used by prep (write) and tile (read).

// Pack two fp32 -> packed bf16 pair (round-half-up via +0x8000, take hi16).
// low16 = bf16(a), high16 = bf16(b). HW-verified R2-R4 (absmax 0.0).
__device__ inline unsigned pk_bf16(float a, float b) {
    unsigned ua = __float_as_uint(a) + 0x8000u;
    unsigned ub = __float_as_uint(b) + 0x8000u;
    return __builtin_amdgcn_perm(ub, ua, 0x07060302);
}

// ============================ FAST PATH ============================
// ---- Kernel 1f: swizzle-convert + norms. One wave per 16x32 tile. ----
// 98304 tiles (2 tensors x 24 bc x 64 R x 32 K); grid 24576 x 4 waves.
__global__ __launch_bounds__(256) void prep_kernel(const float* __restrict__ X,
                                                   const float* __restrict__ Y,
                                                   unsigned short* __restrict__ Xsw,
                                                   unsigned short* __restrict__ Ysw,
                                                   float* __restrict__ xn,
                                                   float* __restrict__ yn) {
    int wave = threadIdx.x >> 6, lane = threadIdx.x & 63;
    int gtile = blockIdx.x * 4 + wave;            // 0 .. 98303
    bool isY = gtile >= 49152;
    int tile = isY ? gtile - 49152 : gtile;       // bc*2048 + R*32 + K
    int bc = tile >> 11;
    int rk = tile & 2047;
    int R = rk >> 5, K = rk & 31;
    int r16 = lane & 15, quad = lane >> 4;

    const float* src = (isY ? Y : X) + ((size_t)bc * N + R * 16 + r16) * D + K * 32 + quad * 8;
    float4 a = *(const float4*)src;
    float4 b = *(const float4*)(src + 4);

    uint4 pk;
    pk.x = pk_bf16(a.x, a.y); pk.y = pk_bf16(a.z, a.w);
    pk.z = pk_bf16(b.x, b.y); pk.w = pk_bf16(b.z, b.w);
    unsigned short* dst = (isY ? Ysw : Xsw) + (size_t)tile * 512 + lane * 8;
    *(uint4*)dst = pk;   // wave = contiguous 1 KB store

    // Row-norm partial for this 32-k span: reduce over the 4 quads (lane bits 4..5).
    float s = a.x * a.x + a.y * a.y + a.z * a.z + a.w * a.w
            + b.x * b.x + b.y * b.y + b.z * b.z + b.w * b.w;
    s += __shfl_xor(s, 16, 64);
    s += __shfl_xor(s, 32, 64);
    if (quad == 0)
        atomicAdd(&(isY ? yn : xn)[bc * N + R * 16 + r16], s);  // 32 contenders/row
}

// ---- Kernel 2f: zero-LDS MFMA tile kernel; frags straight from swizzled global ----
__global__ __launch_bounds__(256) void tile_bf16_kernel(const unsigned short* __restrict__ Xsw,
                                                        const unsigned short* __restrict__ Ysw,
                                                        const float* __restrict__ xn,
                                                        const float* __restrict__ yn,
                                                        unsigned* __restrict__ rowmin,
                                                        unsigned* __restrict__ colmin) {
    // XCD-locality remap (round-robin heuristic: id%8 -> XCD). Each XCD owns 3 bc's
    // (12 MB working set). If the mapping differs, only locality suffers.
    int id = blockIdx.x;              // 0..1535
    int xcd = id & 7, q = id >> 3;    // q 0..191
    int bc = xcd * 3 + (q >> 6);
    int txy = q & 63;
    int tm = txy & 7, tn = txy >> 3;

    int wave = threadIdx.x >> 6, lane = threadIdx.x & 63;
    int wr = wave >> 1, wc = wave & 1;      // wave tile: rows wr*64, cols wc*64
    int quad = lane >> 4, tx = lane & 15;

    const unsigned short* Xb = Xsw + (size_t)bc * 2048 * 512;
    const unsigned short* Yb = Ysw + (size_t)bc * 2048 * 512;
    // af[mi]: tileR = tn*8 + wr*4 + mi; bg[mj]: tileR = tm*8 + wc*4 + mj; tileK = d.
    const unsigned short* ax = Xb + (size_t)(tn * 8 + wr * 4) * 32 * 512 + lane * 8;
    const unsigned short* by = Yb + (size_t)(tm * 8 + wc * 4) * 32 * 512 + lane * 8;

    f32x4 acc[4][4];
    #pragma unroll
    for (int i = 0; i < 4; i++)
        #pragma unroll
        for (int j = 0; j < 4; j++) acc[i][j] = (f32x4)0.f;

    // 2-deep register pipeline over the 32 K-doses; no LDS, no barriers.
    short8 af[2][4], bg[2][4];
    #pragma unroll
    for (int mi = 0; mi < 4; mi++) {
        af[0][mi] = *(const short8*)(ax + mi * 16384);
        bg[0][mi] = *(const short8*)(by + mi * 16384);
    }
    #pragma unroll 2
    for (int d = 0; d < 32; d++) {
        int cur = d & 1, nxt = cur ^ 1;
        if (d < 31) {
            #pragma unroll
            for (int mi = 0; mi < 4; mi++) {
                af[nxt][mi] = *(const short8*)(ax + mi * 16384 + (d + 1) * 512);
                bg[nxt][mi] = *(const short8*)(by + mi * 16384 + (d + 1) * 512);
            }
        }
        #pragma unroll
        for (int mi = 0; mi < 4; mi++)
            #pragma unroll
            for (int mj = 0; mj < 4; mj++)
                acc[mi][mj] = __builtin_amdgcn_mfma_f32_16x16x32_bf16(af[cur][mi], bg[cur][mj], acc[mi][mj], 0, 0, 0);
    }

    // Epilogue. D-layout: row = quad*4 + r (X row), col = tx (Y row) per 16x16 tile.
    int rbase = bc * N + tn * TILE + wr * 64;
    int cbase = bc * N + tm * TILE + wc * 64;
    float xnr[4][4], ynr[4];
    #pragma unroll
    for (int mi = 0; mi < 4; mi++)
        #pragma unroll
        for (int r = 0; r < 4; r++) xnr[mi][r] = xn[rbase + mi * 16 + quad * 4 + r];
    #pragma unroll
    for (int mj = 0; mj < 4; mj++) ynr[mj] = yn[cbase + mj * 16 + tx];

    float rmin[4][4], cmin[4];
    #pragma unroll
    for (int mi = 0; mi < 4; mi++)
        #pragma unroll
        for (int r = 0; r < 4; r++) rmin[mi][r] = FINF;
    #pragma unroll
    for (int mj = 0; mj < 4; mj++) cmin[mj] = FINF;

    #pragma unroll
    for (int mi = 0; mi < 4; mi++)
        #pragma unroll
        for (int mj = 0; mj < 4; mj++)
            #pragma unroll
            for (int r = 0; r < 4; r++) {
                float d2 = fmaxf(xnr[mi][r] + ynr[mj] - 2.f * acc[mi][mj][r], 0.f);
                rmin[mi][r] = fminf(rmin[mi][r], d2);
                cmin[mj]    = fminf(cmin[mj], d2);
            }

    #pragma unroll
    for (int m = 1; m < 16; m <<= 1)
        #pragma unroll
        for (int mi = 0; mi < 4; mi++)
            #pragma unroll
            for (int r = 0; r < 4; r++)
                rmin[mi][r] = fminf(rmin[mi][r], __shfl_xor(rmin[mi][r], m, 64));
    if (tx == 0) {
        #pragma unroll
        for (int mi = 0; mi < 4; mi++)
            #pragma unroll
            for (int r = 0; r < 4; r++)
                atomicMin(&rowmin[rbase + mi * 16 + quad * 4 + r], __float_as_uint(rmin[mi][r]));
    }
    #pragma unroll
    for (int m = 16; m < 64; m <<= 1)
        #pragma unroll
        for (int mj = 0; mj < 4; mj++)
            cmin[mj] = fminf(cmin[mj], __shfl_xor(cmin[mj], m, 64));
    if (quad == 0) {
        #pragma unroll
        for (int mj = 0; mj < 4; mj++)
            atomicMin(&colmin[cbase + mj * 16 + tx], __float_as_uint(cmin[mj]));
    }
}

// ============================ FALLBACK PATH (R2, proven) ============================
__global__ __launch_bounds__(256) void norms_kernel(const float* __restrict__ X,
                                                    const float* __restrict__ Y,
                                                    float* __restrict__ xn,
                                                    float* __restrict__ yn) {
    int w = threadIdx.x >> 6, lane = threadIdx.x & 63;
    long rid = (long)blockIdx.x * 4 + w;
    bool isY = rid >= (long)BC * N;
    long row = isY ? rid - (long)BC * N : rid;
    const float* src = (isY ? Y : X) + row * D;
    float s = 0.f;
    #pragma unroll
    for (int q = 0; q < 4; q++) {
        float4 v = ((const float4*)src)[lane + q * 64];
        s += v.x * v.x + v.y * v.y + v.z * v.z + v.w * v.w;
    }
    #pragma unroll
    for (int m = 1; m < 64; m <<= 1) s += __shfl_xor(s, m, 64);
    if (lane == 0) (isY ? yn : xn)[row] = s;
}

__global__ __launch_bounds__(256) void tile_conv_kernel(const float* __restrict__ X,
                                                        const float* __restrict__ Y,
                                                        const float* __restrict__ xn,
                                                        const float* __restrict__ yn,
                                                        unsigned* __restrict__ rowmin,
                                                        unsigned* __restrict__ colmin) {
    __shared__ unsigned short Xs[TILE * SKF];
    __shared__ unsigned short Ys[TILE * SKF];
    int bc = blockIdx.z, tn = blockIdx.y, tm = blockIdx.x;
    const float* Xb = X + ((size_t)bc * N + (size_t)tn * TILE) * D;
    const float* Yb = Y + ((size_t)bc * N + (size_t)tm * TILE) * D;

    int t = threadIdx.x;
    int srow = t >> 3, sq = t & 7;
    int wave = t >> 6, lane = t & 63;
    int wr = wave >> 1, wc = wave & 1;
    int quad = lane >> 4, tx = lane & 15;

    f32x4 acc[4][4];
    #pragma unroll
    for (int i = 0; i < 4; i++)
        #pragma unroll
        for (int j = 0; j < 4; j++) acc[i][j] = (f32x4)0.f;

    float4 xv[4], yv[4];
    #pragma unroll
    for (int i = 0; i < 4; i++) {
        xv[i] = *(const float4*)(Xb + (size_t)(srow + i * 32) * D + sq * 4);
        yv[i] = *(const float4*)(Yb + (size_t)(srow + i * 32) * D + sq * 4);
    }

    for (int k0 = 0; k0 < D; k0 += 32) {
        __syncthreads();
        #pragma unroll
        for (int i = 0; i < 4; i++) {
            uint2 px; px.x = pk_bf16(xv[i].x, xv[i].y); px.y = pk_bf16(xv[i].z, xv[i].w);
            *(uint2*)&Xs[(srow + i * 32) * SKF + sq * 4] = px;
            uint2 py; py.x = pk_bf16(yv[i].x, yv[i].y); py.y = pk_bf16(yv[i].z, yv[i].w);
            *(uint2*)&Ys[(srow + i * 32) * SKF + sq * 4] = py;
        }
        __syncthreads();
        if (k0 + 32 < D) {
            #pragma unroll
            for (int i = 0; i < 4; i++) {
                xv[i] = *(const float4*)(Xb + (size_t)(srow + i * 32) * D + k0 + 32 + sq * 4);
                yv[i] = *(const float4*)(Yb + (size_t)(srow + i * 32) * D + k0 + 32 + sq * 4);
            }
        }
        short8 af[4], bg[4];
        #pragma unroll
        for (int mi = 0; mi < 4; mi++)
            af[mi] = *(const short8*)&Xs[(wr * 64 + mi * 16 + tx) * SKF + quad * 8];
        #pragma unroll
        for (int mj = 0; mj < 4; mj++)
            bg[mj] = *(const short8*)&Ys[(wc * 64 + mj * 16 + tx) * SKF + quad * 8];
        #pragma unroll
        for (int mi = 0; mi < 4; mi++)
            #pragma unroll
            for (int mj = 0; mj < 4; mj++)
                acc[mi][mj] = __builtin_amdgcn_mfma_f32_16x16x32_bf16(af[mi], bg[mj], acc[mi][mj], 0, 0, 0);
    }

    int rbase = bc * N + tn * TILE + wr * 64;
    int cbase = bc * N + tm * TILE + wc * 64;
    float xnr[4][4], ynr[4];
    #pragma unroll
    for (int mi = 0; mi < 4; mi++)
        #pragma unroll
        for (int r = 0; r < 4; r++) xnr[mi][r] = xn[rbase + mi * 16 + quad * 4 + r];
    #pragma unroll
    for (int mj = 0; mj < 4; mj++) ynr[mj] = yn[cbase + mj * 16 + tx];

    float rmin[4][4], cmin[4];
    #pragma unroll
    for (int mi = 0; mi < 4; mi++)
        #pragma unroll
        for (int r = 0; r < 4; r++) rmin[mi][r] = FINF;
    #pragma unroll
    for (int mj = 0; mj < 4; mj++) cmin[mj] = FINF;

    #pragma unroll
    for (int mi = 0; mi < 4; mi++)
        #pragma unroll
        for (int mj = 0; mj < 4; mj++)
            #pragma unroll
            for (int r = 0; r < 4; r++) {
                float d2 = fmaxf(xnr[mi][r] + ynr[mj] - 2.f * acc[mi][mj][r], 0.f);
                rmin[mi][r] = fminf(rmin[mi][r], d2);
                cmin[mj]    = fminf(cmin[mj], d2);
            }

    #pragma unroll
    for (int m = 1; m < 16; m <<= 1)
        #pragma unroll
        for (int mi = 0; mi < 4; mi++)
            #pragma unroll
            for (int r = 0; r < 4; r++)
                rmin[mi][r] = fminf(rmin[mi][r], __shfl_xor(rmin[mi][r], m, 64));
    if (tx == 0) {
        #pragma unroll
        for (int mi = 0; mi < 4; mi++)
            #pragma unroll
            for (int r = 0; r < 4; r++)
                atomicMin(&rowmin[rbase + mi * 16 + quad * 4 + r], __float_as_uint(rmin[mi][r]));
    }
    #pragma unroll
    for (int m = 16; m < 64; m <<= 1)
        #pragma unroll
        for (int mj = 0; mj < 4; mj++)
            cmin[mj] = fminf(cmin[mj], __shfl_xor(cmin[mj], m, 64));
    if (quad == 0) {
        #pragma unroll
        for (int mj = 0; mj < 4; mj++)
            atomicMin(&colmin[cbase + mj * 16 + tx], __float_as_uint(cmin[mj]));
    }
}

// ---- Kernel 3: per-bc max over row/col mins, sqrt, mean over bc ----
__global__ __launch_bounds__(256) void finalize_kernel(const unsigned* __restrict__ rowmin,
                                                       const unsigned* __restrict__ colmin,
                                                       float* __restrict__ out) {
    int bc = blockIdx.x;
    float v = 0.f;
    for (int i = threadIdx.x; i < N; i += 256) {
        v = fmaxf(v, __uint_as_float(rowmin[bc * N + i]));
        v = fmaxf(v, __uint_as_float(colmin[bc * N + i]));
    }
    #pragma unroll
    for (int m = 1; m < 64; m <<= 1) v = fmaxf(v, __shfl_xor(v, m, 64));
    __shared__ float ws[4];
    int lane = threadIdx.x & 63, w = threadIdx.x >> 6;
    if (lane == 0) ws[w] = v;
    __syncthreads();
    if (threadIdx.x == 0) {
        float m = fmaxf(fmaxf(ws[0], ws[1]), fmaxf(ws[2], ws[3]));
        atomicAdd(out, sqrtf(m) * (1.0f / (float)BC));
    }
}

extern "C" void kernel_launch(void* const* d_in, const int* in_sizes, int n_in,
                              void* d_out, int out_size, void* d_ws, size_t ws_size,
                              hipStream_t stream) {
    const float* X = (const float*)d_in[0];   // input  [8,3,1024,1024]
    const float* Y = (const float*)d_in[1];   // target [8,3,1024,1024]
    float* out = (float*)d_out;               // scalar

    // ws layout: rowmin[24K u32] | colmin[24K u32] | xn[24K f32] | yn[24K f32] | Xsw | Ysw
    unsigned* rowmin = (unsigned*)d_ws;
    unsigned* colmin = rowmin + BC * N;
    float* xn = (float*)(colmin + BC * N);
    float* yn = xn + BC * N;
    size_t head = (size_t)4 * BC * N * 4;            // 384 KB
    size_t bf_bytes = (size_t)BC * N * D * 2;        // 50.33 MB each

    // ws_size is constant across calls, so this branch is graph-capture safe.
    if (ws_size >= head + 2 * bf_bytes) {
        unsigned short* Xsw = (unsigned short*)((char*)d_ws + head);
        unsigned short* Ysw = Xsw + (size_t)BC * N * D;
        hipMemsetAsync(d_ws, 0xFF, (size_t)2 * BC * N * 4, stream);   // rowmin/colmin = +inf bits
        hipMemsetAsync(xn, 0, (size_t)2 * BC * N * 4, stream);        // xn/yn = 0 (atomic targets)
        hipMemsetAsync(d_out, 0, sizeof(float), stream);
        prep_kernel<<<24576, 256, 0, stream>>>(X, Y, Xsw, Ysw, xn, yn);
        tile_bf16_kernel<<<1536, 256, 0, stream>>>(Xsw, Ysw, xn, yn, rowmin, colmin);
    } else {
        hipMemsetAsync(d_ws, 0xFF, (size_t)2 * BC * N * 4, stream);
        hipMemsetAsync(d_out, 0, sizeof(float), stream);
        dim3 grid(N / TILE, N / TILE, BC);
        norms_kernel<<<2 * BC * N / 4, 256, 0, stream>>>(X, Y, xn, yn);
        tile_conv_kernel<<<grid, 256, 0, stream>>>(X, Y, xn, yn, rowmin, colmin);
    }
    finalize_kernel<<<BC, 256, 0, stream>>>(rowmin, colmin, out);
}

// Round 6
// 270.253 us; speedup vs baseline: 1.1211x; 1.1211x over previous
//
#include <hip/hip_runtime.h>
#include <math.h>

// Problem constants (fixed by reference: B=8, C=3, H=W=1024)
constexpr int BC = 24;     // B*C point-set pairs
constexpr int N  = 1024;   // points per set
constexpr int D  = 1024;   // point dimension
constexpr int TILE = 128;  // 128x128 output tile per block
constexpr int SKF = 40;    // fallback kernel LDS stride (bf16)

typedef short short8 __attribute__((ext_vector_type(8)));
typedef float f32x4  __attribute__((ext_vector_type(4)));
typedef long lng2    __attribute__((ext_vector_type(2)));   // two i64 fp8 fragments

#define FINF 3.402823466e+38f

// ---- Swizzled fp8 layout (used identically by prep-write and tile-read) ----
// Super-tile ST = (bc, R = row>>4, Kp = k>>6): 16 rows x 64 k = 1024 fp8 = 1 KB.
// Within: r16 = row&15, dose = (k>>5)&1, quad = (k>>3)&3, j = k&7.
// lane = r16 | (quad<<4); flat byte = ST*1024 + lane*16 + dose*8 + j.
// A wave's fragment pair (doses 0,1 of one 16-row tile) = one coalesced 1-KB
// global_load_dwordx4 (16 B/lane). Within-i64 k-order cancels between A and B.

// Pack two fp32 -> two bf16 (fallback path only). HW-verified R2-R5.
__device__ inline unsigned pk_bf16(float a, float b) {
    unsigned ua = __float_as_uint(a) + 0x8000u;
    unsigned ub = __float_as_uint(b) + 0x8000u;
    return __builtin_amdgcn_perm(ub, ua, 0x07060302);
}

// 4 floats -> one 32-bit word of 4 fp8-e4m3 (OCP on gfx950), RTNE.
__device__ inline int pk_fp8x4(float a, float b, float c, float d) {
    int w = __builtin_amdgcn_cvt_pk_fp8_f32(a, b, 0, false);   // bytes 0,1
    w = __builtin_amdgcn_cvt_pk_fp8_f32(c, d, w, true);        // bytes 2,3
    return w;
}

// ============================ FAST PATH ============================
// ---- Kernel 1f: persistent pipelined swizzle-convert (fp32 -> fp8) + norms ----
// 49152 super-tiles total (2 tensors x 24576); 3072 blocks x 4 waves x 4 STs.
__global__ __launch_bounds__(256) void prep_kernel(const float* __restrict__ X,
                                                   const float* __restrict__ Y,
                                                   unsigned char* __restrict__ Xf8,
                                                   unsigned char* __restrict__ Yf8,
                                                   float* __restrict__ xn,
                                                   float* __restrict__ yn) {
    int wave = threadIdx.x >> 6, lane = threadIdx.x & 63;
    int r16 = lane & 15, quad = lane >> 4;
    int wid = blockIdx.x * 4 + wave;              // 0 .. 12287

    // Stage register sets for 2-deep software pipeline.
    float4 c0, c1, c2, c3;                        // current ST's 16 floats
    float4 n0, n1, n2, n3;                        // next ST's 16 floats

    // st -> source pointer for this lane (k-span: Kp*64 + dose*32 + quad*8).
    auto src_of = [&](int st) -> const float* {
        bool isY = st >= 24576;
        int s = isY ? st - 24576 : s = st;
        s = isY ? st - 24576 : st;
        int bc = s >> 10, rkp = s & 1023;
        int R = rkp >> 4, Kp = rkp & 15;
        return (isY ? Y : X) + ((size_t)bc * N + R * 16 + r16) * D + Kp * 64 + quad * 8;
    };

    {   // prologue: load ST for it=0
        const float* p = src_of(wid);
        c0 = *(const float4*)p;        c1 = *(const float4*)(p + 4);
        c2 = *(const float4*)(p + 32); c3 = *(const float4*)(p + 36);
    }
    #pragma unroll
    for (int it = 0; it < 4; it++) {
        int st = wid + it * 12288;
        if (it < 3) {   // issue next ST's loads before converting current
            const float* p = src_of(wid + (it + 1) * 12288);
            n0 = *(const float4*)p;        n1 = *(const float4*)(p + 4);
            n2 = *(const float4*)(p + 32); n3 = *(const float4*)(p + 36);
        }
        bool isY = st >= 24576;
        int s = isY ? st - 24576 : st;
        uint4 w;
        w.x = (unsigned)pk_fp8x4(c0.x, c0.y, c0.z, c0.w);   // dose0 j0..3
        w.y = (unsigned)pk_fp8x4(c1.x, c1.y, c1.z, c1.w);   // dose0 j4..7
        w.z = (unsigned)pk_fp8x4(c2.x, c2.y, c2.z, c2.w);   // dose1 j0..3
        w.w = (unsigned)pk_fp8x4(c3.x, c3.y, c3.z, c3.w);   // dose1 j4..7
        *(uint4*)((isY ? Yf8 : Xf8) + (size_t)s * 1024 + lane * 16) = w;

        // Row-norm partial (exact fp32) for this 64-k span; reduce over quads.
        float sm = c0.x*c0.x + c0.y*c0.y + c0.z*c0.z + c0.w*c0.w
                 + c1.x*c1.x + c1.y*c1.y + c1.z*c1.z + c1.w*c1.w
                 + c2.x*c2.x + c2.y*c2.y + c2.z*c2.z + c2.w*c2.w
                 + c3.x*c3.x + c3.y*c3.y + c3.z*c3.z + c3.w*c3.w;
        sm += __shfl_xor(sm, 16, 64);
        sm += __shfl_xor(sm, 32, 64);
        if (quad == 0) {
            int bc = s >> 10, R = (s & 1023) >> 4;
            atomicAdd(&(isY ? yn : xn)[bc * N + R * 16 + r16], sm);
        }
        c0 = n0; c1 = n1; c2 = n2; c3 = n3;
    }
}

// ---- Kernel 2f: zero-LDS fp8 MFMA tile kernel; frags straight from swizzled L2/L3 ----
__global__ __launch_bounds__(256, 3) void tile_f8_kernel(const unsigned char* __restrict__ Xf8,
                                                         const unsigned char* __restrict__ Yf8,
                                                         const float* __restrict__ xn,
                                                         const float* __restrict__ yn,
                                                         unsigned* __restrict__ rowmin,
                                                         unsigned* __restrict__ colmin) {
    int id = blockIdx.x;              // 0..1535; same-bc blocks are dispatch-adjacent
    int bc = id >> 6;
    int tn = (id >> 3) & 7, tm = id & 7;

    int wave = threadIdx.x >> 6, lane = threadIdx.x & 63;
    int wr = wave >> 1, wc = wave & 1;      // wave tile: rows wr*64, cols wc*64
    int quad = lane >> 4, tx = lane & 15;

    const unsigned char* Xb = Xf8 + (size_t)bc * 1024 * 1024;   // 1024 STs x 1 KB per bc
    const unsigned char* Yb = Yf8 + (size_t)bc * 1024 * 1024;
    // A STs: R = tn*8 + wr*4 + mi (mi stride = 16 STs = 16 KB); Kp stride = 1 KB.
    const unsigned char* ax = Xb + (size_t)(tn * 8 + wr * 4) * 16 * 1024 + lane * 16;
    const unsigned char* by = Yb + (size_t)(tm * 8 + wc * 4) * 16 * 1024 + lane * 16;

    f32x4 acc[4][4];
    #pragma unroll
    for (int i = 0; i < 4; i++)
        #pragma unroll
        for (int j = 0; j < 4; j++) acc[i][j] = (f32x4)0.f;

    // 2-deep register pipeline over 16 Kp super-doses (2 MFMA doses each).
    lng2 a[2][4], b[2][4];
    #pragma unroll
    for (int mi = 0; mi < 4; mi++) {
        a[0][mi] = *(const lng2*)(ax + mi * 16384);
        b[0][mi] = *(const lng2*)(by + mi * 16384);
    }
    #pragma unroll
    for (int Kp = 0; Kp < 16; Kp++) {
        int cur = Kp & 1, nxt = cur ^ 1;
        if (Kp < 15) {
            #pragma unroll
            for (int mi = 0; mi < 4; mi++) {
                a[nxt][mi] = *(const lng2*)(ax + mi * 16384 + (Kp + 1) * 1024);
                b[nxt][mi] = *(const lng2*)(by + mi * 16384 + (Kp + 1) * 1024);
            }
        }
        #pragma unroll
        for (int mi = 0; mi < 4; mi++)
            #pragma unroll
            for (int mj = 0; mj < 4; mj++)
                acc[mi][mj] = __builtin_amdgcn_mfma_f32_16x16x32_fp8_fp8(a[cur][mi].x, b[cur][mj].x, acc[mi][mj], 0, 0, 0);
        #pragma unroll
        for (int mi = 0; mi < 4; mi++)
            #pragma unroll
            for (int mj = 0; mj < 4; mj++)
                acc[mi][mj] = __builtin_amdgcn_mfma_f32_16x16x32_fp8_fp8(a[cur][mi].y, b[cur][mj].y, acc[mi][mj], 0, 0, 0);
    }

    // Epilogue. D-layout (shape-determined, dtype-independent): row = quad*4 + r, col = tx.
    int rbase = bc * N + tn * TILE + wr * 64;
    int cbase = bc * N + tm * TILE + wc * 64;
    float xnr[4][4], ynr[4];
    #pragma unroll
    for (int mi = 0; mi < 4; mi++)
        #pragma unroll
        for (int r = 0; r < 4; r++) xnr[mi][r] = xn[rbase + mi * 16 + quad * 4 + r];
    #pragma unroll
    for (int mj = 0; mj < 4; mj++) ynr[mj] = yn[cbase + mj * 16 + tx];

    float rmin[4][4], cmin[4];
    #pragma unroll
    for (int mi = 0; mi < 4; mi++)
        #pragma unroll
        for (int r = 0; r < 4; r++) rmin[mi][r] = FINF;
    #pragma unroll
    for (int mj = 0; mj < 4; mj++) cmin[mj] = FINF;

    #pragma unroll
    for (int mi = 0; mi < 4; mi++)
        #pragma unroll
        for (int mj = 0; mj < 4; mj++)
            #pragma unroll
            for (int r = 0; r < 4; r++) {
                float d2 = fmaxf(xnr[mi][r] + ynr[mj] - 2.f * acc[mi][mj][r], 0.f);
                rmin[mi][r] = fminf(rmin[mi][r], d2);
                cmin[mj]    = fminf(cmin[mj], d2);
            }

    #pragma unroll
    for (int m = 1; m < 16; m <<= 1)
        #pragma unroll
        for (int mi = 0; mi < 4; mi++)
            #pragma unroll
            for (int r = 0; r < 4; r++)
                rmin[mi][r] = fminf(rmin[mi][r], __shfl_xor(rmin[mi][r], m, 64));
    if (tx == 0) {
        #pragma unroll
        for (int mi = 0; mi < 4; mi++)
            #pragma unroll
            for (int r = 0; r < 4; r++)
                atomicMin(&rowmin[rbase + mi * 16 + quad * 4 + r], __float_as_uint(rmin[mi][r]));
    }
    #pragma unroll
    for (int m = 16; m < 64; m <<= 1)
        #pragma unroll
        for (int mj = 0; mj < 4; mj++)
            cmin[mj] = fminf(cmin[mj], __shfl_xor(cmin[mj], m, 64));
    if (quad == 0) {
        #pragma unroll
        for (int mj = 0; mj < 4; mj++)
            atomicMin(&colmin[cbase + mj * 16 + tx], __float_as_uint(cmin[mj]));
    }
}

// ============================ FALLBACK PATH (R2, proven) ============================
__global__ __launch_bounds__(256) void norms_kernel(const float* __restrict__ X,
                                                    const float* __restrict__ Y,
                                                    float* __restrict__ xn,
                                                    float* __restrict__ yn) {
    int w = threadIdx.x >> 6, lane = threadIdx.x & 63;
    long rid = (long)blockIdx.x * 4 + w;
    bool isY = rid >= (long)BC * N;
    long row = isY ? rid - (long)BC * N : rid;
    const float* src = (isY ? Y : X) + row * D;
    float s = 0.f;
    #pragma unroll
    for (int q = 0; q < 4; q++) {
        float4 v = ((const float4*)src)[lane + q * 64];
        s += v.x * v.x + v.y * v.y + v.z * v.z + v.w * v.w;
    }
    #pragma unroll
    for (int m = 1; m < 64; m <<= 1) s += __shfl_xor(s, m, 64);
    if (lane == 0) (isY ? yn : xn)[row] = s;
}

__global__ __launch_bounds__(256) void tile_conv_kernel(const float* __restrict__ X,
                                                        const float* __restrict__ Y,
                                                        const float* __restrict__ xn,
                                                        const float* __restrict__ yn,
                                                        unsigned* __restrict__ rowmin,
                                                        unsigned* __restrict__ colmin) {
    __shared__ unsigned short Xs[TILE * SKF];
    __shared__ unsigned short Ys[TILE * SKF];
    int bc = blockIdx.z, tn = blockIdx.y, tm = blockIdx.x;
    const float* Xb = X + ((size_t)bc * N + (size_t)tn * TILE) * D;
    const float* Yb = Y + ((size_t)bc * N + (size_t)tm * TILE) * D;

    int t = threadIdx.x;
    int srow = t >> 3, sq = t & 7;
    int wave = t >> 6, lane = t & 63;
    int wr = wave >> 1, wc = wave & 1;
    int quad = lane >> 4, tx = lane & 15;

    f32x4 acc[4][4];
    #pragma unroll
    for (int i = 0; i < 4; i++)
        #pragma unroll
        for (int j = 0; j < 4; j++) acc[i][j] = (f32x4)0.f;

    float4 xv[4], yv[4];
    #pragma unroll
    for (int i = 0; i < 4; i++) {
        xv[i] = *(const float4*)(Xb + (size_t)(srow + i * 32) * D + sq * 4);
        yv[i] = *(const float4*)(Yb + (size_t)(srow + i * 32) * D + sq * 4);
    }

    for (int k0 = 0; k0 < D; k0 += 32) {
        __syncthreads();
        #pragma unroll
        for (int i = 0; i < 4; i++) {
            uint2 px; px.x = pk_bf16(xv[i].x, xv[i].y); px.y = pk_bf16(xv[i].z, xv[i].w);
            *(uint2*)&Xs[(srow + i * 32) * SKF + sq * 4] = px;
            uint2 py; py.x = pk_bf16(yv[i].x, yv[i].y); py.y = pk_bf16(yv[i].z, yv[i].w);
            *(uint2*)&Ys[(srow + i * 32) * SKF + sq * 4] = py;
        }
        __syncthreads();
        if (k0 + 32 < D) {
            #pragma unroll
            for (int i = 0; i < 4; i++) {
                xv[i] = *(const float4*)(Xb + (size_t)(srow + i * 32) * D + k0 + 32 + sq * 4);
                yv[i] = *(const float4*)(Yb + (size_t)(srow + i * 32) * D + k0 + 32 + sq * 4);
            }
        }
        short8 af[4], bg[4];
        #pragma unroll
        for (int mi = 0; mi < 4; mi++)
            af[mi] = *(const short8*)&Xs[(wr * 64 + mi * 16 + tx) * SKF + quad * 8];
        #pragma unroll
        for (int mj = 0; mj < 4; mj++)
            bg[mj] = *(const short8*)&Ys[(wc * 64 + mj * 16 + tx) * SKF + quad * 8];
        #pragma unroll
        for (int mi = 0; mi < 4; mi++)
            #pragma unroll
            for (int mj = 0; mj < 4; mj++)
                acc[mi][mj] = __builtin_amdgcn_mfma_f32_16x16x32_bf16(af[mi], bg[mj], acc[mi][mj], 0, 0, 0);
    }

    int rbase = bc * N + tn * TILE + wr * 64;
    int cbase = bc * N + tm * TILE + wc * 64;
    float xnr[4][4], ynr[4];
    #pragma unroll
    for (int mi = 0; mi < 4; mi++)
        #pragma unroll
        for (int r = 0; r < 4; r++) xnr[mi][r] = xn[rbase + mi * 16 + quad * 4 + r];
    #pragma unroll
    for (int mj = 0; mj < 4; mj++) ynr[mj] = yn[cbase + mj * 16 + tx];

    float rmin[4][4], cmin[4];
    #pragma unroll
    for (int mi = 0; mi < 4; mi++)
        #pragma unroll
        for (int r = 0; r < 4; r++) rmin[mi][r] = FINF;
    #pragma unroll
    for (int mj = 0; mj < 4; mj++) cmin[mj] = FINF;

    #pragma unroll
    for (int mi = 0; mi < 4; mi++)
        #pragma unroll
        for (int mj = 0; mj < 4; mj++)
            #pragma unroll
            for (int r = 0; r < 4; r++) {
                float d2 = fmaxf(xnr[mi][r] + ynr[mj] - 2.f * acc[mi][mj][r], 0.f);
                rmin[mi][r] = fminf(rmin[mi][r], d2);
                cmin[mj]    = fminf(cmin[mj], d2);
            }

    #pragma unroll
    for (int m = 1; m < 16; m <<= 1)
        #pragma unroll
        for (int mi = 0; mi < 4; mi++)
            #pragma unroll
            for (int r = 0; r < 4; r++)
                rmin[mi][r] = fminf(rmin[mi][r], __shfl_xor(rmin[mi][r], m, 64));
    if (tx == 0) {
        #pragma unroll
        for (int mi = 0; mi < 4; mi++)
            #pragma unroll
            for (int r = 0; r < 4; r++)
                atomicMin(&rowmin[rbase + mi * 16 + quad * 4 + r], __float_as_uint(rmin[mi][r]));
    }
    #pragma unroll
    for (int m = 16; m < 64; m <<= 1)
        #pragma unroll
        for (int mj = 0; mj < 4; mj++)
            cmin[mj] = fminf(cmin[mj], __shfl_xor(cmin[mj], m, 64));
    if (quad == 0) {
        #pragma unroll
        for (int mj = 0; mj < 4; mj++)
            atomicMin(&colmin[cbase + mj * 16 + tx], __float_as_uint(cmin[mj]));
    }
}

// ---- Kernel 3: per-bc max over row/col mins, sqrt, mean over bc ----
__global__ __launch_bounds__(256) void finalize_kernel(const unsigned* __restrict__ rowmin,
                                                       const unsigned* __restrict__ colmin,
                                                       float* __restrict__ out) {
    int bc = blockIdx.x;
    float v = 0.f;
    for (int i = threadIdx.x; i < N; i += 256) {
        v = fmaxf(v, __uint_as_float(rowmin[bc * N + i]));
        v = fmaxf(v, __uint_as_float(colmin[bc * N + i]));
    }
    #pragma unroll
    for (int m = 1; m < 64; m <<= 1) v = fmaxf(v, __shfl_xor(v, m, 64));
    __shared__ float ws[4];
    int lane = threadIdx.x & 63, w = threadIdx.x >> 6;
    if (lane == 0) ws[w] = v;
    __syncthreads();
    if (threadIdx.x == 0) {
        float m = fmaxf(fmaxf(ws[0], ws[1]), fmaxf(ws[2], ws[3]));
        atomicAdd(out, sqrtf(m) * (1.0f / (float)BC));
    }
}

extern "C" void kernel_launch(void* const* d_in, const int* in_sizes, int n_in,
                              void* d_out, int out_size, void* d_ws, size_t ws_size,
                              hipStream_t stream) {
    const float* X = (const float*)d_in[0];   // input  [8,3,1024,1024]
    const float* Y = (const float*)d_in[1];   // target [8,3,1024,1024]
    float* out = (float*)d_out;               // scalar

    // ws layout: rowmin[24K u32] | colmin[24K u32] | xn[24K f32] | yn[24K f32] | Xf8 | Yf8
    unsigned* rowmin = (unsigned*)d_ws;
    unsigned* colmin = rowmin + BC * N;
    float* xn = (float*)(colmin + BC * N);
    float* yn = xn + BC * N;
    size_t head = (size_t)4 * BC * N * 4;            // 384 KB
    size_t f8_bytes = (size_t)BC * N * D;            // 25.17 MB each

    hipMemsetAsync(d_ws, 0xFF, (size_t)2 * BC * N * 4, stream);   // rowmin/colmin = +inf bits
    hipMemsetAsync(xn, 0, (size_t)2 * BC * N * 4, stream);        // xn/yn = 0 (atomic targets)
    hipMemsetAsync(d_out, 0, sizeof(float), stream);

    // ws_size is constant across calls, so this branch is graph-capture safe.
    if (ws_size >= head + 2 * f8_bytes) {
        unsigned char* Xf8 = (unsigned char*)d_ws + head;
        unsigned char* Yf8 = Xf8 + f8_bytes;
        prep_kernel<<<3072, 256, 0, stream>>>(X, Y, Xf8, Yf8, xn, yn);
        tile_f8_kernel<<<1536, 256, 0, stream>>>(Xf8, Yf8, xn, yn, rowmin, colmin);
    } else {
        dim3 grid(N / TILE, N / TILE, BC);
        norms_kernel<<<2 * BC * N / 4, 256, 0, stream>>>(X, Y, xn, yn);
        tile_conv_kernel<<<grid, 256, 0, stream>>>(X, Y, xn, yn, rowmin, colmin);
    }
    finalize_kernel<<<BC, 256, 0, stream>>>(rowmin, colmin, out);
}